// Round 1
// baseline (2447.236 us; speedup 1.0000x reference)
//
#include <hip/hip_runtime.h>

#define NNODES 50000
#define NEDGES 250000
#define NTYPES 3

__device__ __forceinline__ float lrelu(float x, float s) { return x >= 0.f ? x : s * x; }

// order-preserving float<->uint encoding for atomicMax-based segment max
__device__ __forceinline__ unsigned enc_f32(float f) {
    unsigned u = __float_as_uint(f);
    return (u & 0x80000000u) ? ~u : (u | 0x80000000u);
}
__device__ __forceinline__ float dec_f32(unsigned u) {
    return (u & 0x80000000u) ? __uint_as_float(u & 0x7fffffffu) : __uint_as_float(~u);
}

// ---------------------------------------------------------------- build x
__global__ void build_x_kernel(const int* __restrict__ cat, const float* __restrict__ cont,
                               const float* __restrict__ e0, const float* __restrict__ e1,
                               const float* __restrict__ e2, float* __restrict__ x) {
    int n = blockIdx.x * blockDim.x + threadIdx.x;
    if (n >= NNODES) return;
    int c0 = cat[n * 3 + 0], c1 = cat[n * 3 + 1], c2 = cat[n * 3 + 2];
    float* xr = x + (size_t)n * 34;
#pragma unroll
    for (int k = 0; k < 8; k++) xr[k] = e0[c0 * 8 + k];
#pragma unroll
    for (int k = 0; k < 3; k++) xr[8 + k] = e1[c1 * 3 + k];
#pragma unroll
    for (int k = 0; k < 6; k++) xr[11 + k] = e2[c2 * 6 + k];
#pragma unroll
    for (int k = 0; k < 17; k++) xr[17 + k] = cont[n * 17 + k];
}

// ---------------------------------------------------------------- GEMM C = A(NxK) * B(KxM)
// 64x64 tile, 256 threads, 4x4 microtile, 16-deep K staging in LDS.
__global__ void gemm64_kernel(const float* __restrict__ A, const float* __restrict__ B,
                              float* __restrict__ C, int N, int K, int M) {
    __shared__ float Ast[16][68]; // [k][r] transposed A tile
    __shared__ float Bs[16][68];  // [k][c]
    int i0 = blockIdx.x * 64, j0 = blockIdx.y * 64;
    int tid = threadIdx.x;
    int tx = tid & 15, ty = tid >> 4;
    float acc[4][4] = {};
    for (int kk = 0; kk < K; kk += 16) {
#pragma unroll
        for (int it = 0; it < 4; it++) {
            int e = tid + it * 256;
            int r = e >> 4, k = e & 15;
            int gr = i0 + r, gk = kk + k;
            float v = 0.f;
            if (gr < N && gk < K) v = A[(long)gr * K + gk];
            Ast[k][r] = v;
        }
#pragma unroll
        for (int it = 0; it < 4; it++) {
            int e = tid + it * 256;
            int k = e >> 6, c = e & 63;
            int gk = kk + k, gc = j0 + c;
            float v = 0.f;
            if (gk < K && gc < M) v = B[(long)gk * M + gc];
            Bs[k][c] = v;
        }
        __syncthreads();
#pragma unroll
        for (int k = 0; k < 16; k++) {
            float4 a = *(const float4*)&Ast[k][ty * 4];
            float4 b = *(const float4*)&Bs[k][tx * 4];
            float av[4] = {a.x, a.y, a.z, a.w};
            float bv[4] = {b.x, b.y, b.z, b.w};
#pragma unroll
            for (int i = 0; i < 4; i++)
#pragma unroll
                for (int j = 0; j < 4; j++) acc[i][j] += av[i] * bv[j];
        }
        __syncthreads();
    }
#pragma unroll
    for (int i = 0; i < 4; i++) {
        int gr = i0 + ty * 4 + i;
        if (gr >= N) continue;
#pragma unroll
        for (int j = 0; j < 4; j++) {
            int gc = j0 + tx * 4 + j;
            if (gc < M) C[(long)gr * M + gc] = acc[i][j];
        }
    }
}

// ---------------------------------------------------------------- attention logits per node
__global__ void el_er_kernel(const float* __restrict__ feat, const float* __restrict__ al,
                             const float* __restrict__ ar, float* __restrict__ el,
                             float* __restrict__ er, int H, int D) {
    int idx = blockIdx.x * blockDim.x + threadIdx.x;
    if (idx >= NNODES * H) return;
    int n = idx / H, h = idx % H;
    const float4* f4 = (const float4*)(feat + (size_t)n * H * D + h * D);
    const float4* al4 = (const float4*)(al + h * D);
    const float4* ar4 = (const float4*)(ar + h * D);
    float sl = 0.f, sr = 0.f;
    for (int d = 0; d < D / 4; d++) {
        float4 v = f4[d], a = al4[d], b = ar4[d];
        sl += v.x * a.x + v.y * a.y + v.z * a.z + v.w * a.w;
        sr += v.x * b.x + v.y * b.y + v.z * b.z + v.w * b.w;
    }
    el[idx] = sl;
    er[idx] = sr;
}

// ---------------------------------------------------------------- edge pass A: logits + segment max
__global__ void edge_a_kernel(const int* __restrict__ src, const int* __restrict__ dst,
                              const float* __restrict__ el, const float* __restrict__ er,
                              float* __restrict__ ebuf, unsigned* __restrict__ emax, int H) {
    int i = blockIdx.x * blockDim.x + threadIdx.x;
    if (i >= NEDGES) return;
    int s = src[i], d = dst[i];
    for (int h = 0; h < H; h++) {
        float e = lrelu(el[s * H + h] + er[d * H + h], 0.2f);
        ebuf[(size_t)i * H + h] = e;
        atomicMax(&emax[d * H + h], enc_f32(e));
    }
}

// ---------------------------------------------------------------- edge pass B: exp + segment sum
__global__ void edge_b_kernel(const int* __restrict__ dst, const unsigned* __restrict__ emax,
                              float* __restrict__ ebuf, float* __restrict__ den, int H) {
    int i = blockIdx.x * blockDim.x + threadIdx.x;
    if (i >= NEDGES) return;
    int d = dst[i];
    for (int h = 0; h < H; h++) {
        float m = dec_f32(emax[d * H + h]);
        float ee = __expf(ebuf[(size_t)i * H + h] - m);
        ebuf[(size_t)i * H + h] = ee;
        unsafeAtomicAdd(&den[d * H + h], ee);
    }
}

// ---------------------------------------------------------------- edge pass C: weighted scatter
__global__ void edge_c_kernel(const int* __restrict__ src, const int* __restrict__ dst,
                              const float* __restrict__ ebuf, const float* __restrict__ den,
                              const float* __restrict__ feat, float* __restrict__ rst,
                              int H, int D) {
    long gid = (long)blockIdx.x * blockDim.x + threadIdx.x;
    int HD = H * D;
    if (gid >= (long)NEDGES * HD) return;
    int i = (int)(gid / HD), j = (int)(gid % HD);
    int h = j / D;
    int s = src[i], d = dst[i];
    float alpha = ebuf[(size_t)i * H + h] / den[d * H + h];
    unsafeAtomicAdd(&rst[(size_t)d * HD + j], feat[(size_t)s * HD + j] * alpha);
}

// ---------------------------------------------------------------- finish: +bias, lrelu(0.01), mean-accumulate
__global__ void finish_kernel(const float* __restrict__ rst, const float* __restrict__ b,
                              float* __restrict__ hout, int HD) {
    int idx = blockIdx.x * blockDim.x + threadIdx.x;
    if (idx >= NNODES * HD) return;
    int j = idx % HD;
    hout[idx] += lrelu(rst[idx] + b[j], 0.01f) * (1.f / 3.f);
}

// ---------------------------------------------------------------- host-side layer driver
static void run_layer(const float* hin, int K, int H, int D, const float* W,
                      const float* al, const float* ar, const float* b,
                      const int* src_all, const int* dst_all, float* hout, float* feat,
                      float* rst, float* den, unsigned* emaxu, float* el, float* er,
                      float* ebuf, hipStream_t stream) {
    int HD = H * D;
    hipMemsetAsync(hout, 0, (size_t)NNODES * HD * 4, stream);
    for (int t = 0; t < NTYPES; t++) {
        const int* src = src_all + (size_t)t * NEDGES;
        const int* dst = dst_all + (size_t)t * NEDGES;
        dim3 gg((NNODES + 63) / 64, (HD + 63) / 64);
        gemm64_kernel<<<gg, 256, 0, stream>>>(hin, W + (size_t)t * K * HD, feat, NNODES, K, HD);
        el_er_kernel<<<(NNODES * H + 255) / 256, 256, 0, stream>>>(feat, al + t * HD, ar + t * HD,
                                                                   el, er, H, D);
        hipMemsetAsync(rst, 0, (size_t)NNODES * HD * 4, stream);
        hipMemsetAsync(den, 0, (size_t)NNODES * H * 4, stream);
        hipMemsetAsync(emaxu, 0, (size_t)NNODES * H * 4, stream);
        edge_a_kernel<<<(NEDGES + 255) / 256, 256, 0, stream>>>(src, dst, el, er, ebuf, emaxu, H);
        edge_b_kernel<<<(NEDGES + 255) / 256, 256, 0, stream>>>(dst, emaxu, ebuf, den, H);
        long tot = (long)NEDGES * HD;
        edge_c_kernel<<<(int)((tot + 255) / 256), 256, 0, stream>>>(src, dst, ebuf, den, feat, rst,
                                                                    H, D);
        finish_kernel<<<(NNODES * HD + 255) / 256, 256, 0, stream>>>(rst, b + t * HD, hout, HD);
    }
}

extern "C" void kernel_launch(void* const* d_in, const int* in_sizes, int n_in, void* d_out,
                              int out_size, void* d_ws, size_t ws_size, hipStream_t stream) {
    const int* cat = (const int*)d_in[0];
    const float* cont = (const float*)d_in[1];
    const int* src = (const int*)d_in[2];
    const int* dst = (const int*)d_in[3];
    const float* emb0 = (const float*)d_in[4];
    const float* emb1 = (const float*)d_in[5];
    const float* emb2 = (const float*)d_in[6];
    const float* W1 = (const float*)d_in[7];
    const float* al1 = (const float*)d_in[8];
    const float* ar1 = (const float*)d_in[9];
    const float* b1 = (const float*)d_in[10];
    const float* W2 = (const float*)d_in[11];
    const float* al2 = (const float*)d_in[12];
    const float* ar2 = (const float*)d_in[13];
    const float* b2 = (const float*)d_in[14];
    const float* W3 = (const float*)d_in[15];
    const float* al3 = (const float*)d_in[16];
    const float* ar3 = (const float*)d_in[17];
    const float* b3 = (const float*)d_in[18];

    float* ws = (float*)d_ws;
    const size_t NH = (size_t)NNODES * 192;
    float* h1 = ws;             // N*192
    float* h2 = h1 + NH;        // N*192  (x aliases its start; x dead before layer2 writes h2)
    float* x = h2;              // N*34
    float* feat = h2 + NH;      // N*192
    float* rst = feat + NH;     // N*192
    float* den = rst + NH;      // N*3
    unsigned* emaxu = (unsigned*)(den + (size_t)NNODES * 3);  // N*3
    float* el = (float*)emaxu + (size_t)NNODES * 3;           // N*3
    float* er = el + (size_t)NNODES * 3;                      // N*3
    float* ebuf = er + (size_t)NNODES * 3;                    // E*3

    build_x_kernel<<<(NNODES + 255) / 256, 256, 0, stream>>>(cat, cont, emb0, emb1, emb2, x);

    // layer 1: 34 -> (3,64)
    run_layer(x, 34, 3, 64, W1, al1, ar1, b1, src, dst, h1, feat, rst, den, emaxu, el, er, ebuf,
              stream);
    // layer 2: 192 -> (3,64)
    run_layer(h1, 192, 3, 64, W2, al2, ar2, b2, src, dst, h2, feat, rst, den, emaxu, el, er, ebuf,
              stream);
    // layer 3: 192 -> (1,32)  -> d_out
    run_layer(h2, 192, 1, 32, W3, al3, ar3, b3, src, dst, (float*)d_out, feat, rst, den, emaxu, el,
              er, ebuf, stream);
}

// Round 2
// 1269.462 us; speedup vs baseline: 1.9278x; 1.9278x over previous
//
#include <hip/hip_runtime.h>

#define NNODES 50000
#define NEDGES 250000
#define NTYPES 3
#define SCAN_B ((NNODES + 255) / 256)   // 196 blocks per etype

__device__ __forceinline__ float lrelu(float x, float s) { return x >= 0.f ? x : s * x; }

// ---------------------------------------------------------------- build x
__global__ void build_x_kernel(const int* __restrict__ cat, const float* __restrict__ cont,
                               const float* __restrict__ e0, const float* __restrict__ e1,
                               const float* __restrict__ e2, float* __restrict__ x) {
    int n = blockIdx.x * blockDim.x + threadIdx.x;
    if (n >= NNODES) return;
    int c0 = cat[n * 3 + 0], c1 = cat[n * 3 + 1], c2 = cat[n * 3 + 2];
    float* xr = x + (size_t)n * 34;
#pragma unroll
    for (int k = 0; k < 8; k++) xr[k] = e0[c0 * 8 + k];
#pragma unroll
    for (int k = 0; k < 3; k++) xr[8 + k] = e1[c1 * 3 + k];
#pragma unroll
    for (int k = 0; k < 6; k++) xr[11 + k] = e2[c2 * 6 + k];
#pragma unroll
    for (int k = 0; k < 17; k++) xr[17 + k] = cont[n * 17 + k];
}

// ---------------------------------------------------------------- CSR build
__global__ void hist_kernel(const int* __restrict__ dst, int* __restrict__ deg) {
    int idx = blockIdx.x * blockDim.x + threadIdx.x;
    if (idx >= NTYPES * NEDGES) return;
    int t = idx / NEDGES;
    atomicAdd(&deg[t * NNODES + dst[idx]], 1);
}

__global__ void scan1_kernel(const int* __restrict__ deg, int* __restrict__ rowptr,
                             int* __restrict__ bsum) {
    __shared__ int sd[256];
    int t = blockIdx.y, b = blockIdx.x, tid = threadIdx.x;
    int n = b * 256 + tid;
    int v = (n < NNODES) ? deg[t * NNODES + n] : 0;
    sd[tid] = v;
    __syncthreads();
    for (int off = 1; off < 256; off <<= 1) {
        int x = 0;
        if (tid >= off) x = sd[tid - off];
        __syncthreads();
        if (tid >= off) sd[tid] += x;
        __syncthreads();
    }
    int incl = sd[tid];
    if (n < NNODES) rowptr[(size_t)t * (NNODES + 1) + n] = incl - v;  // exclusive
    if (tid == 255) bsum[t * SCAN_B + b] = incl;
}

__global__ void scan2_kernel(int* __restrict__ bsum, int* __restrict__ rowptr) {
    int t = threadIdx.x;
    if (t >= NTYPES) return;
    int run = 0;
    for (int i = 0; i < SCAN_B; i++) {
        int v = bsum[t * SCAN_B + i];
        bsum[t * SCAN_B + i] = run;
        run += v;
    }
    rowptr[(size_t)t * (NNODES + 1) + NNODES] = run;  // == NEDGES
}

__global__ void scan3_kernel(const int* __restrict__ bsum, int* __restrict__ rowptr) {
    int t = blockIdx.y, b = blockIdx.x;
    int n = b * 256 + threadIdx.x;
    if (n < NNODES) rowptr[(size_t)t * (NNODES + 1) + n] += bsum[t * SCAN_B + b];
}

__global__ void scatter_kernel(const int* __restrict__ src, const int* __restrict__ dst,
                               const int* __restrict__ rowptr, int* __restrict__ cursor,
                               int* __restrict__ csrc) {
    int idx = blockIdx.x * blockDim.x + threadIdx.x;
    if (idx >= NTYPES * NEDGES) return;
    int t = idx / NEDGES;
    int s = src[idx], d = dst[idx];
    int pos = rowptr[(size_t)t * (NNODES + 1) + d] + atomicAdd(&cursor[t * NNODES + d], 1);
    csrc[(size_t)t * NEDGES + pos] = s;
}

// ---------------------------------------------------------------- GEMM C = A(NxK) * B(KxM)
__global__ void gemm64_kernel(const float* __restrict__ A, const float* __restrict__ B,
                              float* __restrict__ C, int N, int K, int M) {
    __shared__ float Ast[16][68];
    __shared__ float Bs[16][68];
    int i0 = blockIdx.x * 64, j0 = blockIdx.y * 64;
    int tid = threadIdx.x;
    int tx = tid & 15, ty = tid >> 4;
    float acc[4][4] = {};
    for (int kk = 0; kk < K; kk += 16) {
#pragma unroll
        for (int it = 0; it < 4; it++) {
            int e = tid + it * 256;
            int r = e >> 4, k = e & 15;
            int gr = i0 + r, gk = kk + k;
            float v = 0.f;
            if (gr < N && gk < K) v = A[(long)gr * K + gk];
            Ast[k][r] = v;
        }
#pragma unroll
        for (int it = 0; it < 4; it++) {
            int e = tid + it * 256;
            int k = e >> 6, c = e & 63;
            int gk = kk + k, gc = j0 + c;
            float v = 0.f;
            if (gk < K && gc < M) v = B[(long)gk * M + gc];
            Bs[k][c] = v;
        }
        __syncthreads();
#pragma unroll
        for (int k = 0; k < 16; k++) {
            float4 a = *(const float4*)&Ast[k][ty * 4];
            float4 b = *(const float4*)&Bs[k][tx * 4];
            float av[4] = {a.x, a.y, a.z, a.w};
            float bv[4] = {b.x, b.y, b.z, b.w};
#pragma unroll
            for (int i = 0; i < 4; i++)
#pragma unroll
                for (int j = 0; j < 4; j++) acc[i][j] += av[i] * bv[j];
        }
        __syncthreads();
    }
#pragma unroll
    for (int i = 0; i < 4; i++) {
        int gr = i0 + ty * 4 + i;
        if (gr >= N) continue;
#pragma unroll
        for (int j = 0; j < 4; j++) {
            int gc = j0 + tx * 4 + j;
            if (gc < M) C[(long)gr * M + gc] = acc[i][j];
        }
    }
}

// ---------------------------------------------------------------- attention logits per node
__global__ void el_er_kernel(const float* __restrict__ feat, const float* __restrict__ al,
                             const float* __restrict__ ar, float* __restrict__ el,
                             float* __restrict__ er, int H, int D) {
    int idx = blockIdx.x * blockDim.x + threadIdx.x;
    if (idx >= NNODES * H) return;
    int n = idx / H, h = idx % H;
    const float4* f4 = (const float4*)(feat + (size_t)n * H * D + h * D);
    const float4* al4 = (const float4*)(al + h * D);
    const float4* ar4 = (const float4*)(ar + h * D);
    float sl = 0.f, sr = 0.f;
    for (int d = 0; d < D / 4; d++) {
        float4 v = f4[d], a = al4[d], b = ar4[d];
        sl += v.x * a.x + v.y * a.y + v.z * a.z + v.w * a.w;
        sr += v.x * b.x + v.y * b.y + v.z * b.z + v.w * b.w;
    }
    el[idx] = sl;
    er[idx] = sr;
}

// ---------------------------------------------------------------- fused softmax + aggregate (wave per node)
template <int H, int D>
__global__ void gat_agg_kernel(const int* __restrict__ rowptr, const int* __restrict__ csrc,
                               const float* __restrict__ el, const float* __restrict__ er,
                               const float* __restrict__ feat, const float* __restrict__ b,
                               float* __restrict__ hout, int first) {
    constexpr int HD = H * D;
    constexpr int ELEMS = (HD + 63) / 64;
    int lane = threadIdx.x & 63;
    int node = blockIdx.x * (blockDim.x >> 6) + (threadIdx.x >> 6);
    if (node >= NNODES) return;
    int rs = rowptr[node], re = rowptr[node + 1];
    float erd[H];
#pragma unroll
    for (int h = 0; h < H; h++) erd[h] = er[node * H + h];
    // pass 1: per-head max over incoming edges (redundant across lanes; deg ~5)
    float m[H];
#pragma unroll
    for (int h = 0; h < H; h++) m[h] = -1e30f;
    for (int k = rs; k < re; k++) {
        int s = csrc[k];
#pragma unroll
        for (int h = 0; h < H; h++) {
            float e = lrelu(el[s * H + h] + erd[h], 0.2f);
            m[h] = fmaxf(m[h], e);
        }
    }
    // pass 2: exp-sum + weighted feature accumulate
    float den[H] = {};
    float acc[ELEMS] = {};
    for (int k = rs; k < re; k++) {
        int s = csrc[k];
        float w[H];
#pragma unroll
        for (int h = 0; h < H; h++) {
            float e = lrelu(el[s * H + h] + erd[h], 0.2f);
            w[h] = __expf(e - m[h]);
            den[h] += w[h];
        }
#pragma unroll
        for (int q = 0; q < ELEMS; q++) {
            int j = lane + q * 64;
            if (HD % 64 == 0 || j < HD) acc[q] += w[j / D] * feat[(size_t)s * HD + j];
        }
    }
    int deg = re - rs;
#pragma unroll
    for (int q = 0; q < ELEMS; q++) {
        int j = lane + q * 64;
        if (HD % 64 == 0 || j < HD) {
            float v = (deg > 0) ? acc[q] / den[j / D] : 0.f;
            v = lrelu(v + b[j], 0.01f) * (1.f / 3.f);
            size_t o = (size_t)node * HD + j;
            if (first)
                hout[o] = v;
            else
                hout[o] += v;
        }
    }
}

// ---------------------------------------------------------------- layer driver
static void run_layer(const float* hin, int K, int H, int D, const float* W, const float* al,
                      const float* ar, const float* b, const int* rowptr, const int* csrc,
                      float* hout, float* feat, float* el, float* er, hipStream_t stream) {
    int HD = H * D;
    for (int t = 0; t < NTYPES; t++) {
        dim3 gg((NNODES + 63) / 64, (HD + 63) / 64);
        gemm64_kernel<<<gg, 256, 0, stream>>>(hin, W + (size_t)t * K * HD, feat, NNODES, K, HD);
        el_er_kernel<<<(NNODES * H + 255) / 256, 256, 0, stream>>>(feat, al + t * HD, ar + t * HD,
                                                                   el, er, H, D);
        int blocks = (NNODES + 3) / 4;  // 4 waves/block, wave per node
        const int* rp = rowptr + (size_t)t * (NNODES + 1);
        const int* cs = csrc + (size_t)t * NEDGES;
        if (D == 64)
            gat_agg_kernel<3, 64><<<blocks, 256, 0, stream>>>(rp, cs, el, er, feat, b + t * HD,
                                                              hout, t == 0);
        else
            gat_agg_kernel<1, 32><<<blocks, 256, 0, stream>>>(rp, cs, el, er, feat, b + t * HD,
                                                              hout, t == 0);
    }
}

extern "C" void kernel_launch(void* const* d_in, const int* in_sizes, int n_in, void* d_out,
                              int out_size, void* d_ws, size_t ws_size, hipStream_t stream) {
    const int* cat = (const int*)d_in[0];
    const float* cont = (const float*)d_in[1];
    const int* src = (const int*)d_in[2];
    const int* dst = (const int*)d_in[3];
    const float* emb0 = (const float*)d_in[4];
    const float* emb1 = (const float*)d_in[5];
    const float* emb2 = (const float*)d_in[6];
    const float* W1 = (const float*)d_in[7];
    const float* al1 = (const float*)d_in[8];
    const float* ar1 = (const float*)d_in[9];
    const float* b1 = (const float*)d_in[10];
    const float* W2 = (const float*)d_in[11];
    const float* al2 = (const float*)d_in[12];
    const float* ar2 = (const float*)d_in[13];
    const float* b2 = (const float*)d_in[14];
    const float* W3 = (const float*)d_in[15];
    const float* al3 = (const float*)d_in[16];
    const float* ar3 = (const float*)d_in[17];
    const float* b3 = (const float*)d_in[18];

    const size_t NH = (size_t)NNODES * 192;
    float* ws = (float*)d_ws;
    float* h1 = ws;            // N*192
    float* h2 = h1 + NH;       // N*192 (x aliases its start; x is dead before layer2 writes h2)
    float* x = h2;             // N*34
    float* feat = h2 + NH;     // N*192
    float* el = feat + NH;     // N*3
    float* er = el + (size_t)NNODES * 3;  // N*3
    int* rowptr = (int*)(er + (size_t)NNODES * 3);         // 3*(N+1)
    int* csrc = rowptr + (size_t)NTYPES * (NNODES + 1);    // 3*E
    int* deg = csrc + (size_t)NTYPES * NEDGES;             // 3*N
    int* cursor = deg + (size_t)NTYPES * NNODES;           // 3*N
    int* bsum = cursor + (size_t)NTYPES * NNODES;          // 3*SCAN_B

    // ---- CSR build (reused by all 3 layers)
    hipMemsetAsync(deg, 0, (size_t)NTYPES * NNODES * 4, stream);
    hipMemsetAsync(cursor, 0, (size_t)NTYPES * NNODES * 4, stream);
    hist_kernel<<<(NTYPES * NEDGES + 255) / 256, 256, 0, stream>>>(dst, deg);
    scan1_kernel<<<dim3(SCAN_B, NTYPES), 256, 0, stream>>>(deg, rowptr, bsum);
    scan2_kernel<<<1, 64, 0, stream>>>(bsum, rowptr);
    scan3_kernel<<<dim3(SCAN_B, NTYPES), 256, 0, stream>>>(bsum, rowptr);
    scatter_kernel<<<(NTYPES * NEDGES + 255) / 256, 256, 0, stream>>>(src, dst, rowptr, cursor,
                                                                      csrc);

    build_x_kernel<<<(NNODES + 255) / 256, 256, 0, stream>>>(cat, cont, emb0, emb1, emb2, x);

    run_layer(x, 34, 3, 64, W1, al1, ar1, b1, rowptr, csrc, h1, feat, el, er, stream);
    run_layer(h1, 192, 3, 64, W2, al2, ar2, b2, rowptr, csrc, h2, feat, el, er, stream);
    run_layer(h2, 192, 1, 32, W3, al3, ar3, b3, rowptr, csrc, (float*)d_out, feat, el, er, stream);
}

// Round 3
// 1073.503 us; speedup vs baseline: 2.2797x; 1.1825x over previous
//
#include <hip/hip_runtime.h>

#define NNODES 50000
#define NEDGES 250000
#define NTYPES 3
#define SCAN_B ((NNODES + 255) / 256)   // 196 blocks per etype

typedef __attribute__((ext_vector_type(8))) short bf16x8;
typedef __attribute__((ext_vector_type(4))) float f32x4;

__device__ __forceinline__ float lrelu(float x, float s) { return x >= 0.f ? x : s * x; }

__device__ __forceinline__ unsigned short bf16_rne(float f) {
    unsigned u = __float_as_uint(f);
    unsigned r = (u + 0x7fffu + ((u >> 16) & 1u)) >> 16;
    return (unsigned short)r;
}

// ---------------------------------------------------------------- build x
__global__ void build_x_kernel(const int* __restrict__ cat, const float* __restrict__ cont,
                               const float* __restrict__ e0, const float* __restrict__ e1,
                               const float* __restrict__ e2, float* __restrict__ x) {
    int n = blockIdx.x * blockDim.x + threadIdx.x;
    if (n >= NNODES) return;
    int c0 = cat[n * 3 + 0], c1 = cat[n * 3 + 1], c2 = cat[n * 3 + 2];
    float* xr = x + (size_t)n * 34;
#pragma unroll
    for (int k = 0; k < 8; k++) xr[k] = e0[c0 * 8 + k];
#pragma unroll
    for (int k = 0; k < 3; k++) xr[8 + k] = e1[c1 * 3 + k];
#pragma unroll
    for (int k = 0; k < 6; k++) xr[11 + k] = e2[c2 * 6 + k];
#pragma unroll
    for (int k = 0; k < 17; k++) xr[17 + k] = cont[n * 17 + k];
}

// ---------------------------------------------------------------- CSR build
__global__ void hist_kernel(const int* __restrict__ dst, int* __restrict__ deg) {
    int idx = blockIdx.x * blockDim.x + threadIdx.x;
    if (idx >= NTYPES * NEDGES) return;
    int t = idx / NEDGES;
    atomicAdd(&deg[t * NNODES + dst[idx]], 1);
}

__global__ void scan1_kernel(const int* __restrict__ deg, int* __restrict__ rowptr,
                             int* __restrict__ bsum) {
    __shared__ int sd[256];
    int t = blockIdx.y, b = blockIdx.x, tid = threadIdx.x;
    int n = b * 256 + tid;
    int v = (n < NNODES) ? deg[t * NNODES + n] : 0;
    sd[tid] = v;
    __syncthreads();
    for (int off = 1; off < 256; off <<= 1) {
        int x = 0;
        if (tid >= off) x = sd[tid - off];
        __syncthreads();
        if (tid >= off) sd[tid] += x;
        __syncthreads();
    }
    int incl = sd[tid];
    if (n < NNODES) rowptr[(size_t)t * (NNODES + 1) + n] = incl - v;  // exclusive
    if (tid == 255) bsum[t * SCAN_B + b] = incl;
}

__global__ void scan2_kernel(int* __restrict__ bsum, int* __restrict__ rowptr) {
    int t = threadIdx.x;
    if (t >= NTYPES) return;
    int run = 0;
    for (int i = 0; i < SCAN_B; i++) {
        int v = bsum[t * SCAN_B + i];
        bsum[t * SCAN_B + i] = run;
        run += v;
    }
    rowptr[(size_t)t * (NNODES + 1) + NNODES] = run;
}

__global__ void scan3_kernel(const int* __restrict__ bsum, int* __restrict__ rowptr) {
    int t = blockIdx.y, b = blockIdx.x;
    int n = b * 256 + threadIdx.x;
    if (n < NNODES) rowptr[(size_t)t * (NNODES + 1) + n] += bsum[t * SCAN_B + b];
}

__global__ void scatter_kernel(const int* __restrict__ src, const int* __restrict__ dst,
                               const int* __restrict__ rowptr, int* __restrict__ cursor,
                               int* __restrict__ csrc) {
    int idx = blockIdx.x * blockDim.x + threadIdx.x;
    if (idx >= NTYPES * NEDGES) return;
    int t = idx / NEDGES;
    int s = src[idx], d = dst[idx];
    int pos = rowptr[(size_t)t * (NNODES + 1) + d] + atomicAdd(&cursor[t * NNODES + d], 1);
    csrc[(size_t)t * NEDGES + pos] = s;
}

// ---------------------------------------------------------------- fp32 -> bf16 hi/lo split
// A: (N, Kin) fp32 -> Ahi/Alo: (N, Kout) bf16, zero-padded. One block per row.
__global__ void convert_A_kernel(const float* __restrict__ A, short* __restrict__ Ahi,
                                 short* __restrict__ Alo, int Kin, int Kout) {
    int n = blockIdx.x;
    int k = threadIdx.x;
    if (k >= Kout) return;
    float a = (k < Kin) ? A[(size_t)n * Kin + k] : 0.f;
    unsigned short h = bf16_rne(a);
    float fh = __uint_as_float(((unsigned)h) << 16);
    unsigned short l = bf16_rne(a - fh);
    Ahi[(size_t)n * Kout + k] = (short)h;
    Alo[(size_t)n * Kout + k] = (short)l;
}

// W: (NT, Kin, HD) fp32 -> Bt hi/lo: (NT*HD, Kout) bf16 (transposed, zero-padded)
__global__ void convert_B_kernel(const float* __restrict__ W, short* __restrict__ Bhi,
                                 short* __restrict__ Blo, int Kin, int Kout, int HD, int M) {
    int idx = blockIdx.x * blockDim.x + threadIdx.x;
    if (idx >= M * Kout) return;
    int m = idx / Kout, k = idx % Kout;
    int t = m / HD, j = m % HD;
    float a = (k < Kin) ? W[((size_t)t * Kin + k) * HD + j] : 0.f;
    unsigned short h = bf16_rne(a);
    float fh = __uint_as_float(((unsigned)h) << 16);
    unsigned short l = bf16_rne(a - fh);
    Bhi[(size_t)m * Kout + k] = (short)h;
    Blo[(size_t)m * Kout + k] = (short)l;
}

// ---------------------------------------------------------------- bf16x3 MFMA GEMM
// C(N,M) = A(N,K) * Bt(M,K)^T with A=Ahi+Alo, B=Bhi+Blo (3-term product).
// 128x128 tile, 4 waves, wave tile 64x64 via 4x4 mfma_f32_16x16x32_bf16 fragments.
// Store splits columns into per-type feat buffers: t = gc/HD, dst = C + t*tstride.
__global__ __launch_bounds__(256) void gemm_mfma_kernel(
    const short* __restrict__ AhiG, const short* __restrict__ AloG,
    const short* __restrict__ BhiG, const short* __restrict__ BloG, float* __restrict__ C,
    int N, int K, int M, int HD, size_t tstride) {
    __shared__ short AsH[128 * 40], AsL[128 * 40], BsH[128 * 40], BsL[128 * 40];
    int tid = threadIdx.x;
    int n0 = blockIdx.x * 128, m0 = blockIdx.y * 128;
    int wid = tid >> 6, lane = tid & 63;
    int wm = (wid >> 1) * 64, wn = (wid & 1) * 64;
    int lrow = lane & 15, kq = (lane >> 4) * 8;
    f32x4 acc[4][4] = {};

    for (int k0 = 0; k0 < K; k0 += 32) {
        __syncthreads();
#pragma unroll
        for (int p = 0; p < 2; p++) {
            int r = (tid >> 2) + p * 64;
            int kq2 = (tid & 3) * 8;
            bf16x8 z = {};
            bf16x8 vh = z, vl = z;
            int gr = n0 + r;
            if (gr < N) {
                size_t o = (size_t)gr * K + k0 + kq2;
                vh = *(const bf16x8*)(AhiG + o);
                vl = *(const bf16x8*)(AloG + o);
            }
            *(bf16x8*)&AsH[r * 40 + kq2] = vh;
            *(bf16x8*)&AsL[r * 40 + kq2] = vl;
            vh = z;
            vl = z;
            int gc = m0 + r;
            if (gc < M) {
                size_t o = (size_t)gc * K + k0 + kq2;
                vh = *(const bf16x8*)(BhiG + o);
                vl = *(const bf16x8*)(BloG + o);
            }
            *(bf16x8*)&BsH[r * 40 + kq2] = vh;
            *(bf16x8*)&BsL[r * 40 + kq2] = vl;
        }
        __syncthreads();
        bf16x8 ah[4], al[4], bh[4], bl[4];
#pragma unroll
        for (int f = 0; f < 4; f++) {
            int ra = (wm + f * 16 + lrow) * 40 + kq;
            ah[f] = *(const bf16x8*)&AsH[ra];
            al[f] = *(const bf16x8*)&AsL[ra];
            int rb = (wn + f * 16 + lrow) * 40 + kq;
            bh[f] = *(const bf16x8*)&BsH[rb];
            bl[f] = *(const bf16x8*)&BsL[rb];
        }
#pragma unroll
        for (int fa = 0; fa < 4; fa++)
#pragma unroll
            for (int fb = 0; fb < 4; fb++) {
                acc[fa][fb] =
                    __builtin_amdgcn_mfma_f32_16x16x32_bf16(al[fa], bh[fb], acc[fa][fb], 0, 0, 0);
                acc[fa][fb] =
                    __builtin_amdgcn_mfma_f32_16x16x32_bf16(ah[fa], bl[fb], acc[fa][fb], 0, 0, 0);
                acc[fa][fb] =
                    __builtin_amdgcn_mfma_f32_16x16x32_bf16(ah[fa], bh[fb], acc[fa][fb], 0, 0, 0);
            }
    }
#pragma unroll
    for (int fb = 0; fb < 4; fb++) {
        int gc = m0 + wn + fb * 16 + lrow;
        if (gc >= M) continue;
        int t = gc / HD, j = gc - t * HD;
        float* dst = C + (size_t)t * tstride + j;
#pragma unroll
        for (int fa = 0; fa < 4; fa++) {
            int rbase = n0 + wm + fa * 16 + (lane >> 4) * 4;
#pragma unroll
            for (int e = 0; e < 4; e++) {
                int gr = rbase + e;
                if (gr < N) dst[(size_t)gr * HD] = acc[fa][fb][e];
            }
        }
    }
}

// ---------------------------------------------------------------- attention logits per node
__global__ void el_er_kernel(const float* __restrict__ feat, const float* __restrict__ al,
                             const float* __restrict__ ar, float* __restrict__ el,
                             float* __restrict__ er, int H, int D) {
    int idx = blockIdx.x * blockDim.x + threadIdx.x;
    if (idx >= NNODES * H) return;
    int n = idx / H, h = idx % H;
    const float4* f4 = (const float4*)(feat + (size_t)n * H * D + h * D);
    const float4* al4 = (const float4*)(al + h * D);
    const float4* ar4 = (const float4*)(ar + h * D);
    float sl = 0.f, sr = 0.f;
    for (int d = 0; d < D / 4; d++) {
        float4 v = f4[d], a = al4[d], b = ar4[d];
        sl += v.x * a.x + v.y * a.y + v.z * a.z + v.w * a.w;
        sr += v.x * b.x + v.y * b.y + v.z * b.z + v.w * b.w;
    }
    el[idx] = sl;
    er[idx] = sr;
}

// ---------------------------------------------------------------- fused softmax + aggregate (wave per node)
template <int H, int D>
__global__ void gat_agg_kernel(const int* __restrict__ rowptr, const int* __restrict__ csrc,
                               const float* __restrict__ el, const float* __restrict__ er,
                               const float* __restrict__ feat, const float* __restrict__ b,
                               float* __restrict__ hout, int first) {
    constexpr int HD = H * D;
    constexpr int ELEMS = (HD + 63) / 64;
    int lane = threadIdx.x & 63;
    int node = blockIdx.x * (blockDim.x >> 6) + (threadIdx.x >> 6);
    if (node >= NNODES) return;
    int rs = rowptr[node], re = rowptr[node + 1];
    float erd[H];
#pragma unroll
    for (int h = 0; h < H; h++) erd[h] = er[node * H + h];
    float m[H];
#pragma unroll
    for (int h = 0; h < H; h++) m[h] = -1e30f;
    for (int k = rs; k < re; k++) {
        int s = csrc[k];
#pragma unroll
        for (int h = 0; h < H; h++) {
            float e = lrelu(el[s * H + h] + erd[h], 0.2f);
            m[h] = fmaxf(m[h], e);
        }
    }
    float den[H] = {};
    float acc[ELEMS] = {};
    for (int k = rs; k < re; k++) {
        int s = csrc[k];
        float w[H];
#pragma unroll
        for (int h = 0; h < H; h++) {
            float e = lrelu(el[s * H + h] + erd[h], 0.2f);
            w[h] = __expf(e - m[h]);
            den[h] += w[h];
        }
#pragma unroll
        for (int q = 0; q < ELEMS; q++) {
            int j = lane + q * 64;
            if (HD % 64 == 0 || j < HD) acc[q] += w[j / D] * feat[(size_t)s * HD + j];
        }
    }
    int deg = re - rs;
#pragma unroll
    for (int q = 0; q < ELEMS; q++) {
        int j = lane + q * 64;
        if (HD % 64 == 0 || j < HD) {
            float v = (deg > 0) ? acc[q] / den[j / D] : 0.f;
            v = lrelu(v + b[j], 0.01f) * (1.f / 3.f);
            size_t o = (size_t)node * HD + j;
            if (first)
                hout[o] = v;
            else
                hout[o] += v;
        }
    }
}

// ---------------------------------------------------------------- layer driver
static void run_layer(const float* hin, int Kin, int Kout, int H, int D, bool batched,
                      const float* W, const float* al, const float* ar, const float* b,
                      const int* rowptr, const int* csrc, float* hout, short* Ahi, short* Alo,
                      short* Bhi, short* Blo, float* feat, float* el, float* er,
                      hipStream_t stream) {
    int HD = H * D;
    int Mall = NTYPES * HD;
    convert_A_kernel<<<NNODES, Kout, 0, stream>>>(hin, Ahi, Alo, Kin, Kout);
    convert_B_kernel<<<(Mall * Kout + 255) / 256, 256, 0, stream>>>(W, Bhi, Blo, Kin, Kout, HD,
                                                                    Mall);
    int gx = (NNODES + 127) / 128;
    if (batched) {
        dim3 gg(gx, (Mall + 127) / 128);
        gemm_mfma_kernel<<<gg, 256, 0, stream>>>(Ahi, Alo, Bhi, Blo, feat, NNODES, Kout, Mall, HD,
                                                 (size_t)NNODES * HD);
    }
    for (int t = 0; t < NTYPES; t++) {
        float* feat_t;
        if (batched) {
            feat_t = feat + (size_t)t * NNODES * HD;
        } else {
            feat_t = feat;
            dim3 gg(gx, (HD + 127) / 128);
            gemm_mfma_kernel<<<gg, 256, 0, stream>>>(Ahi, Alo, Bhi + (size_t)t * HD * Kout,
                                                     Blo + (size_t)t * HD * Kout, feat_t, NNODES,
                                                     Kout, HD, HD, 0);
        }
        el_er_kernel<<<(NNODES * H + 255) / 256, 256, 0, stream>>>(feat_t, al + t * HD, ar + t * HD,
                                                                   el, er, H, D);
        int blocks = (NNODES + 3) / 4;
        const int* rp = rowptr + (size_t)t * (NNODES + 1);
        const int* cs = csrc + (size_t)t * NEDGES;
        if (D == 64)
            gat_agg_kernel<3, 64><<<blocks, 256, 0, stream>>>(rp, cs, el, er, feat_t, b + t * HD,
                                                              hout, t == 0);
        else
            gat_agg_kernel<1, 32><<<blocks, 256, 0, stream>>>(rp, cs, el, er, feat_t, b + t * HD,
                                                              hout, t == 0);
    }
}

extern "C" void kernel_launch(void* const* d_in, const int* in_sizes, int n_in, void* d_out,
                              int out_size, void* d_ws, size_t ws_size, hipStream_t stream) {
    const int* cat = (const int*)d_in[0];
    const float* cont = (const float*)d_in[1];
    const int* src = (const int*)d_in[2];
    const int* dst = (const int*)d_in[3];
    const float* emb0 = (const float*)d_in[4];
    const float* emb1 = (const float*)d_in[5];
    const float* emb2 = (const float*)d_in[6];
    const float* W1 = (const float*)d_in[7];
    const float* al1 = (const float*)d_in[8];
    const float* ar1 = (const float*)d_in[9];
    const float* b1 = (const float*)d_in[10];
    const float* W2 = (const float*)d_in[11];
    const float* al2 = (const float*)d_in[12];
    const float* ar2 = (const float*)d_in[13];
    const float* b2 = (const float*)d_in[14];
    const float* W3 = (const float*)d_in[15];
    const float* al3 = (const float*)d_in[16];
    const float* ar3 = (const float*)d_in[17];
    const float* b3 = (const float*)d_in[18];

    const size_t NH = (size_t)NNODES * 192;
    float* ws = (float*)d_ws;
    float* h1 = ws;         // N*192 f32
    float* h2 = h1 + NH;    // N*192 f32 (x aliases its start; x dead before layer2 writes h2)
    float* x = h2;          // N*34 f32
    float* feat = h2 + NH;  // N*192 f32 (layer3: 3*N*32 fits)
    short* Ahi = (short*)(feat + NH);  // N*192 bf16
    short* Alo = Ahi + NH;             // N*192 bf16
    short* Bhi = Alo + NH;             // up to 576*192 bf16
    short* Blo = Bhi + 576 * 192;
    float* el = (float*)(Blo + 576 * 192);
    float* er = el + (size_t)NNODES * 3;
    int* rowptr = (int*)(er + (size_t)NNODES * 3);       // 3*(N+1)
    int* csrc = rowptr + (size_t)NTYPES * (NNODES + 1);  // 3*E
    int* deg = csrc + (size_t)NTYPES * NEDGES;           // 3*N
    int* cursor = deg + (size_t)NTYPES * NNODES;         // 3*N
    int* bsum = cursor + (size_t)NTYPES * NNODES;        // 3*SCAN_B

    // ---- CSR build (reused by all 3 layers)
    hipMemsetAsync(deg, 0, (size_t)NTYPES * NNODES * 4, stream);
    hipMemsetAsync(cursor, 0, (size_t)NTYPES * NNODES * 4, stream);
    hist_kernel<<<(NTYPES * NEDGES + 255) / 256, 256, 0, stream>>>(dst, deg);
    scan1_kernel<<<dim3(SCAN_B, NTYPES), 256, 0, stream>>>(deg, rowptr, bsum);
    scan2_kernel<<<1, 64, 0, stream>>>(bsum, rowptr);
    scan3_kernel<<<dim3(SCAN_B, NTYPES), 256, 0, stream>>>(bsum, rowptr);
    scatter_kernel<<<(NTYPES * NEDGES + 255) / 256, 256, 0, stream>>>(src, dst, rowptr, cursor,
                                                                      csrc);

    build_x_kernel<<<(NNODES + 255) / 256, 256, 0, stream>>>(cat, cont, emb0, emb1, emb2, x);

    run_layer(x, 34, 64, 3, 64, false, W1, al1, ar1, b1, rowptr, csrc, h1, Ahi, Alo, Bhi, Blo, feat,
              el, er, stream);
    run_layer(h1, 192, 192, 3, 64, false, W2, al2, ar2, b2, rowptr, csrc, h2, Ahi, Alo, Bhi, Blo,
              feat, el, er, stream);
    run_layer(h2, 192, 192, 1, 32, true, W3, al3, ar3, b3, rowptr, csrc, (float*)d_out, Ahi, Alo,
              Bhi, Blo, feat, el, er, stream);
}

// Round 4
// 570.251 us; speedup vs baseline: 4.2915x; 1.8825x over previous
//
#include <hip/hip_runtime.h>

#define NNODES 50000
#define NEDGES 250000
#define NTYPES 3
#define SCAN_B ((NNODES + 255) / 256)   // 196 blocks per etype

typedef __attribute__((ext_vector_type(8))) short bf16x8;
typedef __attribute__((ext_vector_type(4))) float f32x4;

__device__ __forceinline__ float lrelu(float x, float s) { return x >= 0.f ? x : s * x; }

__device__ __forceinline__ unsigned short bf16_rne(float f) {
    unsigned u = __float_as_uint(f);
    unsigned r = (u + 0x7fffu + ((u >> 16) & 1u)) >> 16;
    return (unsigned short)r;
}

// ---------------------------------------------------------------- build x -> bf16 hi/lo (K padded to 64)
__global__ void build_x_kernel(const int* __restrict__ cat, const float* __restrict__ cont,
                               const float* __restrict__ e0, const float* __restrict__ e1,
                               const float* __restrict__ e2, short* __restrict__ Ahi,
                               short* __restrict__ Alo) {
    int n = blockIdx.x * 4 + (threadIdx.x >> 6);
    int k = threadIdx.x & 63;
    if (n >= NNODES) return;
    float v = 0.f;
    if (k < 8) v = e0[cat[n * 3 + 0] * 8 + k];
    else if (k < 11) v = e1[cat[n * 3 + 1] * 3 + (k - 8)];
    else if (k < 17) v = e2[cat[n * 3 + 2] * 6 + (k - 11)];
    else if (k < 34) v = cont[n * 17 + (k - 17)];
    unsigned short h = bf16_rne(v);
    float fh = __uint_as_float(((unsigned)h) << 16);
    unsigned short l = bf16_rne(v - fh);
    Ahi[(size_t)n * 64 + k] = (short)h;
    Alo[(size_t)n * 64 + k] = (short)l;
}

// ---------------------------------------------------------------- CSR build
__global__ void hist_kernel(const int* __restrict__ dst, int* __restrict__ deg) {
    int idx = blockIdx.x * blockDim.x + threadIdx.x;
    if (idx >= NTYPES * NEDGES) return;
    int t = idx / NEDGES;
    atomicAdd(&deg[t * NNODES + dst[idx]], 1);
}

__global__ void scan1_kernel(const int* __restrict__ deg, int* __restrict__ rowptr,
                             int* __restrict__ bsum) {
    __shared__ int sd[256];
    int t = blockIdx.y, b = blockIdx.x, tid = threadIdx.x;
    int n = b * 256 + tid;
    int v = (n < NNODES) ? deg[t * NNODES + n] : 0;
    sd[tid] = v;
    __syncthreads();
    for (int off = 1; off < 256; off <<= 1) {
        int x = 0;
        if (tid >= off) x = sd[tid - off];
        __syncthreads();
        if (tid >= off) sd[tid] += x;
        __syncthreads();
    }
    int incl = sd[tid];
    if (n < NNODES) rowptr[(size_t)t * (NNODES + 1) + n] = incl - v;  // exclusive
    if (tid == 255) bsum[t * SCAN_B + b] = incl;
}

__global__ void scan2_kernel(int* __restrict__ bsum, int* __restrict__ rowptr) {
    int t = threadIdx.x;
    if (t >= NTYPES) return;
    int run = 0;
    for (int i = 0; i < SCAN_B; i++) {
        int v = bsum[t * SCAN_B + i];
        bsum[t * SCAN_B + i] = run;
        run += v;
    }
    rowptr[(size_t)t * (NNODES + 1) + NNODES] = run;
}

__global__ void scan3_kernel(const int* __restrict__ bsum, int* __restrict__ rowptr) {
    int t = blockIdx.y, b = blockIdx.x;
    int n = b * 256 + threadIdx.x;
    if (n < NNODES) rowptr[(size_t)t * (NNODES + 1) + n] += bsum[t * SCAN_B + b];
}

__global__ void scatter_kernel(const int* __restrict__ src, const int* __restrict__ dst,
                               const int* __restrict__ rowptr, int* __restrict__ cursor,
                               int* __restrict__ csrc) {
    int idx = blockIdx.x * blockDim.x + threadIdx.x;
    if (idx >= NTYPES * NEDGES) return;
    int t = idx / NEDGES;
    int s = src[idx], d = dst[idx];
    int pos = rowptr[(size_t)t * (NNODES + 1) + d] + atomicAdd(&cursor[t * NNODES + d], 1);
    csrc[(size_t)t * NEDGES + pos] = s;
}

// ---------------------------------------------------------------- W -> transposed bf16 hi/lo
__global__ void convert_B_kernel(const float* __restrict__ W, short* __restrict__ Bhi,
                                 short* __restrict__ Blo, int Kin, int Kout, int HD, int M) {
    int idx = blockIdx.x * blockDim.x + threadIdx.x;
    if (idx >= M * Kout) return;
    int m = idx / Kout, k = idx % Kout;
    int t = m / HD, j = m % HD;
    float a = (k < Kin) ? W[((size_t)t * Kin + k) * HD + j] : 0.f;
    unsigned short h = bf16_rne(a);
    float fh = __uint_as_float(((unsigned)h) << 16);
    unsigned short l = bf16_rne(a - fh);
    Bhi[(size_t)m * Kout + k] = (short)h;
    Blo[(size_t)m * Kout + k] = (short)l;
}

// ---------------------------------------------------------------- bf16x3 MFMA GEMM
// C(N,M) = A(N,K) * Bt(M,K)^T, A=Ahi+Alo, B=Bhi+Blo. Columns split per etype:
// t = gc/HD, dst = C + t*tstride + row*HD + j  (feat_all[t][n][j]).
__global__ __launch_bounds__(256) void gemm_mfma_kernel(
    const short* __restrict__ AhiG, const short* __restrict__ AloG,
    const short* __restrict__ BhiG, const short* __restrict__ BloG, float* __restrict__ C,
    int N, int K, int M, int HD, size_t tstride) {
    __shared__ short AsH[128 * 40], AsL[128 * 40], BsH[128 * 40], BsL[128 * 40];
    int tid = threadIdx.x;
    int n0 = blockIdx.x * 128, m0 = blockIdx.y * 128;
    int wid = tid >> 6, lane = tid & 63;
    int wm = (wid >> 1) * 64, wn = (wid & 1) * 64;
    int lrow = lane & 15, kq = (lane >> 4) * 8;
    f32x4 acc[4][4] = {};

    for (int k0 = 0; k0 < K; k0 += 32) {
        __syncthreads();
#pragma unroll
        for (int p = 0; p < 2; p++) {
            int r = (tid >> 2) + p * 64;
            int kq2 = (tid & 3) * 8;
            bf16x8 z = {};
            bf16x8 vh = z, vl = z;
            int gr = n0 + r;
            if (gr < N) {
                size_t o = (size_t)gr * K + k0 + kq2;
                vh = *(const bf16x8*)(AhiG + o);
                vl = *(const bf16x8*)(AloG + o);
            }
            *(bf16x8*)&AsH[r * 40 + kq2] = vh;
            *(bf16x8*)&AsL[r * 40 + kq2] = vl;
            vh = z;
            vl = z;
            int gc = m0 + r;
            if (gc < M) {
                size_t o = (size_t)gc * K + k0 + kq2;
                vh = *(const bf16x8*)(BhiG + o);
                vl = *(const bf16x8*)(BloG + o);
            }
            *(bf16x8*)&BsH[r * 40 + kq2] = vh;
            *(bf16x8*)&BsL[r * 40 + kq2] = vl;
        }
        __syncthreads();
        bf16x8 ah[4], al[4], bh[4], bl[4];
#pragma unroll
        for (int f = 0; f < 4; f++) {
            int ra = (wm + f * 16 + lrow) * 40 + kq;
            ah[f] = *(const bf16x8*)&AsH[ra];
            al[f] = *(const bf16x8*)&AsL[ra];
            int rb = (wn + f * 16 + lrow) * 40 + kq;
            bh[f] = *(const bf16x8*)&BsH[rb];
            bl[f] = *(const bf16x8*)&BsL[rb];
        }
#pragma unroll
        for (int fa = 0; fa < 4; fa++)
#pragma unroll
            for (int fb = 0; fb < 4; fb++) {
                acc[fa][fb] =
                    __builtin_amdgcn_mfma_f32_16x16x32_bf16(al[fa], bh[fb], acc[fa][fb], 0, 0, 0);
                acc[fa][fb] =
                    __builtin_amdgcn_mfma_f32_16x16x32_bf16(ah[fa], bl[fb], acc[fa][fb], 0, 0, 0);
                acc[fa][fb] =
                    __builtin_amdgcn_mfma_f32_16x16x32_bf16(ah[fa], bh[fb], acc[fa][fb], 0, 0, 0);
            }
    }
#pragma unroll
    for (int fb = 0; fb < 4; fb++) {
        int gc = m0 + wn + fb * 16 + lrow;
        if (gc >= M) continue;
        int t = gc / HD, j = gc - t * HD;
        float* dst = C + (size_t)t * tstride + j;
#pragma unroll
        for (int fa = 0; fa < 4; fa++) {
            int rbase = n0 + wm + fa * 16 + (lane >> 4) * 4;
#pragma unroll
            for (int e = 0; e < 4; e++) {
                int gr = rbase + e;
                if (gr < N) dst[(size_t)gr * HD] = acc[fa][fb][e];
            }
        }
    }
}

// ---------------------------------------------------------------- attention logits (all etypes)
// el/er stored padded: el_all[(t*N + n)*4 + h]
template <int H, int D>
__global__ void el_er_kernel(const float* __restrict__ feat_all, const float* __restrict__ alw,
                             const float* __restrict__ arw, float* __restrict__ el_all,
                             float* __restrict__ er_all) {
    int idx = blockIdx.x * blockDim.x + threadIdx.x;
    if (idx >= NTYPES * NNODES * H) return;
    int t = idx / (NNODES * H);
    int rem = idx - t * NNODES * H;
    int n = rem / H, h = rem - (rem / H) * H;
    const float4* f4 = (const float4*)(feat_all + ((size_t)t * NNODES + n) * H * D + h * D);
    const float4* a4 = (const float4*)(alw + (t * H + h) * D);
    const float4* b4 = (const float4*)(arw + (t * H + h) * D);
    float sl = 0.f, sr = 0.f;
#pragma unroll
    for (int d = 0; d < D / 4; d++) {
        float4 v = f4[d], a = a4[d], b = b4[d];
        sl += v.x * a.x + v.y * a.y + v.z * a.z + v.w * a.w;
        sr += v.x * b.x + v.y * b.y + v.z * b.z + v.w * b.w;
    }
    el_all[((size_t)t * NNODES + n) * 4 + h] = sl;
    er_all[((size_t)t * NNODES + n) * 4 + h] = sr;
}

// ---------------------------------------------------------------- fused all-etype single-pass agg
// wave per node; single pass (no max-sub: logits bounded, fp32 exp exact enough);
// out written once; optionally as bf16 hi/lo for next layer's GEMM A.
template <int H, int D, int BF16OUT>
__global__ __launch_bounds__(256) void gat_agg_kernel(
    const int* __restrict__ rowptr_all, const int* __restrict__ csrc_all,
    const float* __restrict__ el_all, const float* __restrict__ er_all,
    const float* __restrict__ feat_all, const float* __restrict__ b_all,
    float* __restrict__ fout, short* __restrict__ Ahi, short* __restrict__ Alo) {
    constexpr int HD = H * D;
    constexpr int EL = (HD + 63) / 64;
    int lane = threadIdx.x & 63;
    int node = blockIdx.x * (blockDim.x >> 6) + (threadIdx.x >> 6);
    if (node >= NNODES) return;
    float out[EL] = {};
#pragma unroll 1
    for (int t = 0; t < NTYPES; t++) {
        const int* rowptr = rowptr_all + (size_t)t * (NNODES + 1);
        const int* csrc = csrc_all + (size_t)t * NEDGES;
        const float* el = el_all + (size_t)t * NNODES * 4;
        const float* feat = feat_all + (size_t)t * NNODES * HD;
        float4 er4 = *(const float4*)(er_all + ((size_t)t * NNODES + node) * 4);
        float erd[3] = {er4.x, er4.y, er4.z};
        int rs = rowptr[node], re = rowptr[node + 1];
        float den[H] = {};
        float acc[EL] = {};
        for (int k = rs; k < re; k += 4) {
            int cnt = re - k;
            int s[4];
#pragma unroll
            for (int c = 0; c < 4; c++) s[c] = csrc[k + (c < cnt ? c : 0)];
            float w[4][H];
#pragma unroll
            for (int c = 0; c < 4; c++) {
                float4 e4 = *(const float4*)(el + (size_t)s[c] * 4);
                float ev[3] = {e4.x, e4.y, e4.z};
#pragma unroll
                for (int h = 0; h < H; h++) {
                    float e = lrelu(ev[h] + erd[h], 0.2f);
                    w[c][h] = (c < cnt) ? __expf(e) : 0.f;
                    den[h] += w[c][h];
                }
            }
#pragma unroll
            for (int c = 0; c < 4; c++) {
#pragma unroll
                for (int q = 0; q < EL; q++) {
                    int j = lane + q * 64;
                    constexpr bool full = (HD % 64 == 0);
                    float fv = (full || lane < HD % 64 || q < EL - 1)
                                   ? feat[(size_t)s[c] * HD + j]
                                   : 0.f;
                    int hh = (D == 64) ? q : 0;
                    acc[q] = fmaf(w[c][hh], fv, acc[q]);
                }
            }
        }
        float inv[H];
#pragma unroll
        for (int h = 0; h < H; h++) inv[h] = (re > rs) ? __frcp_rn(den[h]) : 0.f;
#pragma unroll
        for (int q = 0; q < EL; q++) {
            int j = lane + q * 64;
            if (HD % 64 == 0 || j < HD) {
                int hh = (D == 64) ? q : 0;
                float v = acc[q] * inv[hh];
                v = lrelu(v + b_all[t * HD + j], 0.01f);
                out[q] += v * (1.f / 3.f);
            }
        }
    }
#pragma unroll
    for (int q = 0; q < EL; q++) {
        int j = lane + q * 64;
        if (HD % 64 == 0 || j < HD) {
            if (BF16OUT) {
                unsigned short h = bf16_rne(out[q]);
                float fh = __uint_as_float(((unsigned)h) << 16);
                unsigned short l = bf16_rne(out[q] - fh);
                Ahi[(size_t)node * HD + j] = (short)h;
                Alo[(size_t)node * HD + j] = (short)l;
            } else {
                fout[(size_t)node * HD + j] = out[q];
            }
        }
    }
}

extern "C" void kernel_launch(void* const* d_in, const int* in_sizes, int n_in, void* d_out,
                              int out_size, void* d_ws, size_t ws_size, hipStream_t stream) {
    const int* cat = (const int*)d_in[0];
    const float* cont = (const float*)d_in[1];
    const int* src = (const int*)d_in[2];
    const int* dst = (const int*)d_in[3];
    const float* emb0 = (const float*)d_in[4];
    const float* emb1 = (const float*)d_in[5];
    const float* emb2 = (const float*)d_in[6];
    const float* W1 = (const float*)d_in[7];
    const float* al1 = (const float*)d_in[8];
    const float* ar1 = (const float*)d_in[9];
    const float* b1 = (const float*)d_in[10];
    const float* W2 = (const float*)d_in[11];
    const float* al2 = (const float*)d_in[12];
    const float* ar2 = (const float*)d_in[13];
    const float* b2 = (const float*)d_in[14];
    const float* W3 = (const float*)d_in[15];
    const float* al3 = (const float*)d_in[16];
    const float* ar3 = (const float*)d_in[17];
    const float* b3 = (const float*)d_in[18];

    float* ws = (float*)d_ws;
    float* feat_all = ws;                              // 3*N*192 f32 = 115.2 MB
    short* Ahi = (short*)(feat_all + (size_t)3 * NNODES * 192);  // N*192 bf16
    short* Alo = Ahi + (size_t)NNODES * 192;
    short* Bhi = Alo + (size_t)NNODES * 192;           // 576*192 bf16
    short* Blo = Bhi + 576 * 192;
    float* el_all = (float*)(Blo + 576 * 192);         // 3*N*4 f32 (padded)
    float* er_all = el_all + (size_t)3 * NNODES * 4;
    int* rowptr = (int*)(er_all + (size_t)3 * NNODES * 4);  // 3*(N+1)
    int* csrc = rowptr + NTYPES * (NNODES + 1);             // 3*E
    int* deg = csrc + NTYPES * NEDGES;                      // 3*N
    int* cursor = deg + NTYPES * NNODES;                    // 3*N
    int* bsum = cursor + NTYPES * NNODES;                   // 3*SCAN_B

    // ---- CSR build (reused by all 3 layers)
    hipMemsetAsync(deg, 0, (size_t)NTYPES * NNODES * 4, stream);
    hipMemsetAsync(cursor, 0, (size_t)NTYPES * NNODES * 4, stream);
    hist_kernel<<<(NTYPES * NEDGES + 255) / 256, 256, 0, stream>>>(dst, deg);
    scan1_kernel<<<dim3(SCAN_B, NTYPES), 256, 0, stream>>>(deg, rowptr, bsum);
    scan2_kernel<<<1, 64, 0, stream>>>(bsum, rowptr);
    scan3_kernel<<<dim3(SCAN_B, NTYPES), 256, 0, stream>>>(bsum, rowptr);
    scatter_kernel<<<(NTYPES * NEDGES + 255) / 256, 256, 0, stream>>>(src, dst, rowptr, cursor,
                                                                      csrc);

    build_x_kernel<<<(NNODES + 3) / 4, 256, 0, stream>>>(cat, cont, emb0, emb1, emb2, Ahi, Alo);

    const int gx = (NNODES + 127) / 128;
    const int aggb = (NNODES + 3) / 4;

    // ---- layer 1: K=34->64, M=3*192
    convert_B_kernel<<<(576 * 64 + 255) / 256, 256, 0, stream>>>(W1, Bhi, Blo, 34, 64, 192, 576);
    gemm_mfma_kernel<<<dim3(gx, 5), 256, 0, stream>>>(Ahi, Alo, Bhi, Blo, feat_all, NNODES, 64, 576,
                                                      192, (size_t)NNODES * 192);
    el_er_kernel<3, 64><<<(NTYPES * NNODES * 3 + 255) / 256, 256, 0, stream>>>(feat_all, al1, ar1,
                                                                               el_all, er_all);
    gat_agg_kernel<3, 64, 1><<<aggb, 256, 0, stream>>>(rowptr, csrc, el_all, er_all, feat_all, b1,
                                                       nullptr, Ahi, Alo);

    // ---- layer 2: K=192, M=3*192
    convert_B_kernel<<<(576 * 192 + 255) / 256, 256, 0, stream>>>(W2, Bhi, Blo, 192, 192, 192, 576);
    gemm_mfma_kernel<<<dim3(gx, 5), 256, 0, stream>>>(Ahi, Alo, Bhi, Blo, feat_all, NNODES, 192,
                                                      576, 192, (size_t)NNODES * 192);
    el_er_kernel<3, 64><<<(NTYPES * NNODES * 3 + 255) / 256, 256, 0, stream>>>(feat_all, al2, ar2,
                                                                               el_all, er_all);
    gat_agg_kernel<3, 64, 1><<<aggb, 256, 0, stream>>>(rowptr, csrc, el_all, er_all, feat_all, b2,
                                                       nullptr, Ahi, Alo);

    // ---- layer 3: K=192, M=3*32 -> d_out
    convert_B_kernel<<<(96 * 192 + 255) / 256, 256, 0, stream>>>(W3, Bhi, Blo, 192, 192, 32, 96);
    gemm_mfma_kernel<<<dim3(gx, 1), 256, 0, stream>>>(Ahi, Alo, Bhi, Blo, feat_all, NNODES, 192, 96,
                                                      32, (size_t)NNODES * 32);
    el_er_kernel<1, 32><<<(NTYPES * NNODES * 1 + 255) / 256, 256, 0, stream>>>(feat_all, al3, ar3,
                                                                               el_all, er_all);
    gat_agg_kernel<1, 32, 0><<<aggb, 256, 0, stream>>>(rowptr, csrc, el_all, er_all, feat_all, b3,
                                                       (float*)d_out, nullptr, nullptr);
}